// Round 7
// baseline (2267.746 us; speedup 1.0000x reference)
//
#include <hip/hip_runtime.h>
#include <hip/hip_bf16.h>
#include <cstdint>
#include <cstddef>

typedef unsigned short u16;
typedef __attribute__((ext_vector_type(4))) float f32x4;
typedef __attribute__((ext_vector_type(8))) short bf16x8;
typedef __attribute__((ext_vector_type(8))) unsigned short u16x8;
typedef __attribute__((ext_vector_type(4))) unsigned short u16x4;

#define D_LAYERS 8
#define DIMN 1024
#define FFD 4096
#define VOCAB 32000
#define MROWS 4096   /* B*S */
#define SEQ 2048
#define NCHUNK 64
#define LCHUNK 32

// ---------- helpers ----------
__device__ __forceinline__ u16 f2b(float f) {
  union { float f; unsigned u; } v; v.f = f;
  unsigned r = v.u + 0x7FFFu + ((v.u >> 16) & 1u);
  return (u16)(r >> 16);
}
__device__ __forceinline__ float b2f(u16 h) {
  union { unsigned u; float f; } v; v.u = ((unsigned)h) << 16;
  return v.f;
}
__device__ __forceinline__ float sigm(float x) { return 1.f / (1.f + __expf(-x)); }
__device__ __forceinline__ float ftanh(float x) {
  float e = __expf(2.f * x);          // inf for large x -> 1; 0 for very neg -> -1
  return 1.f - 2.f / (e + 1.f);
}

// async global->LDS, 16B per lane. LDS dest is wave-uniform base + lane*16 (HW).
__device__ __forceinline__ void async16(const void* g, void* l) {
  auto gp = reinterpret_cast<const __attribute__((address_space(1))) char*>(
      reinterpret_cast<uintptr_t>(g));
  auto lp = reinterpret_cast<__attribute__((address_space(3))) char*>(
      reinterpret_cast<uintptr_t>(l));
  __builtin_amdgcn_global_load_lds(gp, lp, 16, 0, 0);
}

__device__ __forceinline__ float blk_sum(float v) {
  __shared__ float sm[4];
  #pragma unroll
  for (int o = 32; o > 0; o >>= 1) v += __shfl_xor(v, o);
  if ((threadIdx.x & 63) == 0) sm[threadIdx.x >> 6] = v;
  __syncthreads();
  float r = sm[0] + sm[1] + sm[2] + sm[3];
  __syncthreads();
  return r;
}

// ---------- small kernels ----------
__global__ __launch_bounds__(256) void k_cvt(const f32x4* __restrict__ in,
                                             u16x8* __restrict__ out) {
  size_t i = (size_t)blockIdx.x * 256 + threadIdx.x;
  f32x4 a = in[i * 2], b = in[i * 2 + 1];
  u16x8 o;
  o[0] = f2b(a[0]); o[1] = f2b(a[1]); o[2] = f2b(a[2]); o[3] = f2b(a[3]);
  o[4] = f2b(b[0]); o[5] = f2b(b[1]); o[6] = f2b(b[2]); o[7] = f2b(b[3]);
  out[i] = o;
}

// converts one layer's 7 weight tensors in one launch (8192 blocks x 2048 elems)
__global__ __launch_bounds__(256) void k_cvt7(
    const float* __restrict__ Wf, const float* __restrict__ Wi,
    const float* __restrict__ Wig, const float* __restrict__ Wog,
    const float* __restrict__ Wfc, const float* __restrict__ Wfa,
    const float* __restrict__ Wfo,
    u16* __restrict__ dGates,   // [4 x 1M] bf16, order f,i,ig,og
    u16* __restrict__ dFc, u16* __restrict__ dFa, u16* __restrict__ dFo,
    int L)
{
  const int b = blockIdx.x;  // 0..8191
  const float* src; u16* dst; size_t off;
  if (b < 2048) {
    const int g = b >> 9, r = b & 511;
    const float* s = (g == 0) ? Wf : (g == 1) ? Wi : (g == 2) ? Wig : Wog;
    src = s + (size_t)L * 1048576;
    dst = dGates + (size_t)g * 1048576;
    off = (size_t)r * 2048;
  } else if (b < 4096) {
    src = Wfc + (size_t)L * 4194304; dst = dFc; off = (size_t)(b - 2048) * 2048;
  } else if (b < 6144) {
    src = Wfa + (size_t)L * 4194304; dst = dFa; off = (size_t)(b - 4096) * 2048;
  } else {
    src = Wfo + (size_t)L * 4194304; dst = dFo; off = (size_t)(b - 6144) * 2048;
  }
  const size_t i = off + (size_t)threadIdx.x * 8;
  f32x4 a = *(const f32x4*)(src + i);
  f32x4 c = *(const f32x4*)(src + i + 4);
  u16x8 o;
  o[0] = f2b(a[0]); o[1] = f2b(a[1]); o[2] = f2b(a[2]); o[3] = f2b(a[3]);
  o[4] = f2b(c[0]); o[5] = f2b(c[1]); o[6] = f2b(c[2]); o[7] = f2b(c[3]);
  *(u16x8*)(dst + i) = o;
}

__global__ __launch_bounds__(256) void k_embed(const int* __restrict__ tok,
                                               const float* __restrict__ emb,
                                               float* __restrict__ x) {
  const int r = blockIdx.x;
  const int tk = tok[r];
  f32x4 v = ((const f32x4*)(emb + (size_t)tk * DIMN))[threadIdx.x];
  float ss = v[0]*v[0] + v[1]*v[1] + v[2]*v[2] + v[3]*v[3];
  float tot = blk_sum(ss);
  float nrm = sqrtf(tot);
  float s = (nrm > 1.f) ? (1.f / (nrm + 1e-7f)) : 1.f;
  f32x4 o = {v[0]*s, v[1]*s, v[2]*s, v[3]*s};
  ((f32x4*)(x + (size_t)r * DIMN))[threadIdx.x] = o;
}

__global__ __launch_bounds__(256) void k_rms(const float* __restrict__ x,
                                             const float* __restrict__ wgt,
                                             u16* __restrict__ out) {
  const int r = blockIdx.x;
  f32x4 v = ((const f32x4*)(x + (size_t)r * DIMN))[threadIdx.x];
  float ss = v[0]*v[0] + v[1]*v[1] + v[2]*v[2] + v[3]*v[3];
  float tot = blk_sum(ss);
  float sc = rsqrtf(tot * (1.f / DIMN) + 1e-6f);
  f32x4 w = ((const f32x4*)wgt)[threadIdx.x];
  u16x4 o;
  o[0] = f2b(v[0] * sc * w[0]);
  o[1] = f2b(v[1] * sc * w[1]);
  o[2] = f2b(v[2] * sc * w[2]);
  o[3] = f2b(v[3] * sc * w[3]);
  ((u16x4*)(out + (size_t)r * DIMN))[threadIdx.x] = o;
}

// scan phase A: per-chunk aggregates (A = prod f, V = chunk-local scan end)
__global__ __launch_bounds__(256) void k_scanA(const float* __restrict__ f,
                                               const float* __restrict__ v,
                                               float* __restrict__ Ac,
                                               float* __restrict__ Vc) {
  const int bx = blockIdx.x;              // b*256 + c*4 + dg
  const int dg = bx & 3, c = (bx >> 2) & 63, b = bx >> 8;
  const int d = dg * 256 + threadIdx.x;
  const size_t base = ((size_t)(b * SEQ + c * LCHUNK)) * DIMN + d;
  float a = 1.f, h = 0.f;
  #pragma unroll 4
  for (int t = 0; t < LCHUNK; ++t) {
    size_t ix = base + (size_t)t * DIMN;
    float fv = f[ix];
    h = fv * h + v[ix];
    a *= fv;
  }
  const size_t ci = ((size_t)(b * NCHUNK + c)) * DIMN + d;
  Ac[ci] = a; Vc[ci] = h;
}

// scan phase B: exclusive scan over chunks, init = h0
__global__ __launch_bounds__(256) void k_scanB(const float* __restrict__ Ac,
                                               const float* __restrict__ Vc,
                                               const float* __restrict__ h0,
                                               float* __restrict__ carry) {
  const int idx = blockIdx.x * 256 + threadIdx.x;  // 0..2047
  const int b = idx >> 10, d = idx & 1023;
  float h = h0[d];
  for (int c = 0; c < NCHUNK; ++c) {
    size_t ci = ((size_t)(b * NCHUNK + c)) * DIMN + d;
    carry[ci] = h;
    h = Ac[ci] * h + Vc[ci];
  }
}

// scan phase C: recompute with carry-in, y = tanh(h)*o, x += y
__global__ __launch_bounds__(256) void k_scanC(const float* __restrict__ f,
                                               const float* __restrict__ v,
                                               const float* __restrict__ oo,
                                               const float* __restrict__ carry,
                                               float* __restrict__ x) {
  const int bx = blockIdx.x;
  const int dg = bx & 3, c = (bx >> 2) & 63, b = bx >> 8;
  const int d = dg * 256 + threadIdx.x;
  const size_t base = ((size_t)(b * SEQ + c * LCHUNK)) * DIMN + d;
  float h = carry[((size_t)(b * NCHUNK + c)) * DIMN + d];
  for (int t = 0; t < LCHUNK; ++t) {
    size_t ix = base + (size_t)t * DIMN;
    float fv = f[ix];
    h = fv * h + v[ix];
    x[ix] += ftanh(h) * oo[ix];
  }
}

// split-K reduce: x += p0 + p1 + bias
__global__ __launch_bounds__(256) void k_red(const f32x4* __restrict__ pp,
                                             const float* __restrict__ bias,
                                             float* __restrict__ x) {
  const size_t i = (size_t)blockIdx.x * 256 + threadIdx.x;   // f32x4 index
  const int n4 = (int)(i & 255);                             // DIMN/4 = 256
  f32x4 a = pp[i];
  f32x4 b = pp[i + (size_t)MROWS * DIMN / 4];
  f32x4 bs = ((const f32x4*)bias)[n4];
  f32x4 xv = ((const f32x4*)x)[i];
  f32x4 o = {xv[0] + a[0] + b[0] + bs[0], xv[1] + a[1] + b[1] + bs[1],
             xv[2] + a[2] + b[2] + bs[2], xv[3] + a[3] + b[3] + bs[3]};
  ((f32x4*)x)[i] = o;
}

// ---------- 128-tile GEMM (m97 structure) + XCD-chunked swizzle ----------
// Grid is 1D in x (tiles, %8==0), optional z = split-K part.
// swz=(bid&7)*q+(bid>>3): each XCD gets a contiguous swz range -> contiguous
// n-panels -> B fetched ~once per XCD instead of 8x (T1).
constexpr int EPI_BIAS_F32 = 4, EPI_PART = 5;

template<int BN_T, int EPI>
__global__ __launch_bounds__(256, 2)
void gemm_bt(const u16* __restrict__ A,
             const u16* __restrict__ B0,
             const float* __restrict__ bias0,
             float* __restrict__ oF0,
             int N, int K, int LD, int GX)
{
  constexpr int MF = (BN_T == 128) ? 4 : 2;
  constexpr int WAVES_N = (BN_T == 128) ? 2 : 1;
  constexpr int ISS_B = BN_T / 32;
  __shared__ __align__(16) u16 As[128 * 64];
  __shared__ __align__(16) u16 Bs[BN_T * 64];
  const int tid = threadIdx.x;
  const int w = tid >> 6, lane = tid & 63;
  const int wm = w / WAVES_N, wn = w % WAVES_N;
  const int bid = blockIdx.x;
  const int q = (int)gridDim.x >> 3;
  const int swz = (bid & 7) * q + (bid >> 3);
  const int m0 = (swz % GX) * 128;
  const int n0 = (swz / GX) * BN_T;

  const u16* Aw = A;
  const u16* Bw = B0;
  float* oF = oF0;
  if constexpr (EPI == EPI_PART) {
    const int koff = blockIdx.z * K;       // split-K column offset
    Aw += koff; Bw += koff;
    oF += (size_t)blockIdx.z * MROWS * DIMN;
  }

  const f32x4 zero = {0.f, 0.f, 0.f, 0.f};
  f32x4 acc[MF][4];
  #pragma unroll
  for (int mf = 0; mf < MF; ++mf)
    #pragma unroll
    for (int nf = 0; nf < 4; ++nf) acc[mf][nf] = zero;

  for (int kt = 0; kt < K; kt += 64) {
    #pragma unroll
    for (int i = 0; i < 4; ++i) {
      int p = i * 4096 + w * 1024 + lane * 16;
      int r = p >> 7;
      int cs = (p & 127) ^ ((r & 7) << 4);
      async16(Aw + ((size_t)(m0 + r) * LD + kt) + (cs >> 1),
              (char*)As + i * 4096 + w * 1024);
    }
    #pragma unroll
    for (int i = 0; i < ISS_B; ++i) {
      int p = i * 4096 + w * 1024 + lane * 16;
      int r = p >> 7;
      int cs = (p & 127) ^ ((r & 7) << 4);
      async16(Bw + ((size_t)(n0 + r) * LD + kt) + (cs >> 1),
              (char*)Bs + i * 4096 + w * 1024);
    }
    __syncthreads();
    #pragma unroll
    for (int ks = 0; ks < 2; ++ks) {
      bf16x8 av[MF], bv[4];
      const int cbase = ks * 64 + ((lane >> 4) << 4);
      #pragma unroll
      for (int mf = 0; mf < MF; ++mf) {
        int r = wm * (MF * 16) + mf * 16 + (lane & 15);
        av[mf] = *(const bf16x8*)((const char*)As + r * 128 + (cbase ^ ((r & 7) << 4)));
      }
      #pragma unroll
      for (int nf = 0; nf < 4; ++nf) {
        int r = wn * 64 + nf * 16 + (lane & 15);
        bv[nf] = *(const bf16x8*)((const char*)Bs + r * 128 + (cbase ^ ((r & 7) << 4)));
      }
      #pragma unroll
      for (int mf = 0; mf < MF; ++mf)
        #pragma unroll
        for (int nf = 0; nf < 4; ++nf)
          acc[mf][nf] = __builtin_amdgcn_mfma_f32_16x16x32_bf16(
              av[mf], bv[nf], acc[mf][nf], 0, 0, 0);
    }
    __syncthreads();
  }

  #pragma unroll
  for (int nf = 0; nf < 4; ++nf) {
    const int n = n0 + wn * 64 + nf * 16 + (lane & 15);
    const float bb = (EPI == EPI_PART) ? 0.f : bias0[n];
    #pragma unroll
    for (int mf = 0; mf < MF; ++mf) {
      #pragma unroll
      for (int j = 0; j < 4; ++j) {
        const int m = m0 + wm * (MF * 16) + mf * 16 + ((lane >> 4) << 2) + j;
        const size_t idx = (size_t)m * N + n;
        oF[idx] = acc[mf][nf][j] + bb;
      }
    }
  }
}

// ---------- dual-B 128-tile GEMM: two GEMMs sharing the A-tile ----------
//   EDG (gates, y-routed): y=0: (Wi,Wig) -> v = tanh(va)*sig(vb)
//                          y=1: (Wf,Wog) -> f = sig(va), o = sig(vb)
//   EDF (ffn-up): (Wfa,Wfc) -> u = vb * silu(va)  [bf16]
constexpr int EDG = 0, EDF = 1;

template<int EPI>
__global__ __launch_bounds__(256, 2)
void gemm_dual(const u16* __restrict__ A,
               const u16* __restrict__ Ba0, const u16* __restrict__ Bb0,
               const u16* __restrict__ Ba1, const u16* __restrict__ Bb1,
               const float* __restrict__ ba0, const float* __restrict__ bb0,
               const float* __restrict__ ba1, const float* __restrict__ bb1,
               float* __restrict__ oV,          // y=0 product (gates)
               float* __restrict__ oFa, float* __restrict__ oFb, // y=1 pair
               u16* __restrict__ oU,            // ffn-up bf16
               int N, int K, int GX)
{
  __shared__ __align__(16) u16 As[128 * 64];
  __shared__ __align__(16) u16 Bsa[128 * 64];
  __shared__ __align__(16) u16 Bsb[128 * 64];
  const int tid = threadIdx.x;
  const int w = tid >> 6, lane = tid & 63;
  const int wm = w >> 1, wn = w & 1;
  const int bid = blockIdx.x;
  const int q = (int)gridDim.x >> 3;
  const int swz = (bid & 7) * q + (bid >> 3);
  const int m0 = (swz % GX) * 128;
  const int n0 = (swz / GX) * 128;
  const int z = blockIdx.y;

  const u16* Ba = (EPI == EDG && z) ? Ba1 : Ba0;
  const u16* Bb = (EPI == EDG && z) ? Bb1 : Bb0;
  const float* ba = (EPI == EDG && z) ? ba1 : ba0;
  const float* bb = (EPI == EDG && z) ? bb1 : bb0;

  const f32x4 zero = {0.f, 0.f, 0.f, 0.f};
  f32x4 accA[4][4], accB[4][4];
  #pragma unroll
  for (int mf = 0; mf < 4; ++mf)
    #pragma unroll
    for (int nf = 0; nf < 4; ++nf) { accA[mf][nf] = zero; accB[mf][nf] = zero; }

  for (int kt = 0; kt < K; kt += 64) {
    #pragma unroll
    for (int i = 0; i < 4; ++i) {
      const int p = i * 4096 + w * 1024 + lane * 16;
      const int r = p >> 7;
      const int cs = (p & 127) ^ ((r & 7) << 4);
      async16(A  + ((size_t)(m0 + r) * K + kt) + (cs >> 1),
              (char*)As + i * 4096 + w * 1024);
      async16(Ba + ((size_t)(n0 + r) * K + kt) + (cs >> 1),
              (char*)Bsa + i * 4096 + w * 1024);
      async16(Bb + ((size_t)(n0 + r) * K + kt) + (cs >> 1),
              (char*)Bsb + i * 4096 + w * 1024);
    }
    __syncthreads();
    #pragma unroll
    for (int ks = 0; ks < 2; ++ks) {
      bf16x8 av[4], bva[4], bvb[4];
      const int cbase = ks * 64 + ((lane >> 4) << 4);
      #pragma unroll
      for (int mf = 0; mf < 4; ++mf) {
        const int r = wm * 64 + mf * 16 + (lane & 15);
        av[mf] = *(const bf16x8*)((const char*)As + r * 128 + (cbase ^ ((r & 7) << 4)));
      }
      #pragma unroll
      for (int nf = 0; nf < 4; ++nf) {
        const int r = wn * 64 + nf * 16 + (lane & 15);
        const int off = r * 128 + (cbase ^ ((r & 7) << 4));
        bva[nf] = *(const bf16x8*)((const char*)Bsa + off);
        bvb[nf] = *(const bf16x8*)((const char*)Bsb + off);
      }
      #pragma unroll
      for (int mf = 0; mf < 4; ++mf)
        #pragma unroll
        for (int nf = 0; nf < 4; ++nf) {
          accA[mf][nf] = __builtin_amdgcn_mfma_f32_16x16x32_bf16(
              av[mf], bva[nf], accA[mf][nf], 0, 0, 0);
          accB[mf][nf] = __builtin_amdgcn_mfma_f32_16x16x32_bf16(
              av[mf], bvb[nf], accB[mf][nf], 0, 0, 0);
        }
    }
    __syncthreads();
  }

  #pragma unroll
  for (int nf = 0; nf < 4; ++nf) {
    const int n = n0 + wn * 64 + nf * 16 + (lane & 15);
    const float bba = ba[n], bbb = bb[n];
    #pragma unroll
    for (int mf = 0; mf < 4; ++mf) {
      #pragma unroll
      for (int j = 0; j < 4; ++j) {
        const int m = m0 + wm * 64 + mf * 16 + ((lane >> 4) << 2) + j;
        const size_t idx = (size_t)m * N + n;
        const float va = accA[mf][nf][j] + bba;
        const float vb = accB[mf][nf][j] + bbb;
        if constexpr (EPI == EDG) {
          if (z == 0) {
            oV[idx] = ftanh(va) * sigm(vb);
          } else {
            oFa[idx] = sigm(va);
            oFb[idx] = sigm(vb);
          }
        } else {
          oU[idx] = f2b(vb * va * sigm(va));
        }
      }
    }
  }
}

// ---------- launcher ----------
extern "C" void kernel_launch(void* const* d_in, const int* in_sizes, int n_in,
                              void* d_out, int out_size, void* d_ws, size_t ws_size,
                              hipStream_t stream) {
  (void)in_sizes; (void)n_in; (void)out_size; (void)ws_size;
  const int*   tokens = (const int*)d_in[0];
  const float* emb  = (const float*)d_in[1];
  const float* h0   = (const float*)d_in[2];
  const float* Wf   = (const float*)d_in[3];
  const float* bf_  = (const float*)d_in[4];
  const float* Wi   = (const float*)d_in[5];
  const float* bi_  = (const float*)d_in[6];
  const float* Wig  = (const float*)d_in[7];
  const float* big_ = (const float*)d_in[8];
  const float* Wog  = (const float*)d_in[9];
  const float* bog_ = (const float*)d_in[10];
  const float* n1   = (const float*)d_in[11];
  const float* n2   = (const float*)d_in[12];
  const float* Wfc  = (const float*)d_in[13];
  const float* bfc_ = (const float*)d_in[14];
  const float* Wfa  = (const float*)d_in[15];
  const float* bfa_ = (const float*)d_in[16];
  const float* Wfo  = (const float*)d_in[17];
  const float* bfo_ = (const float*)d_in[18];
  const float* nl_  = (const float*)d_in[19];
  const float* Wout = (const float*)d_in[20];
  const float* bout_= (const float*)d_in[21];
  float* out = (float*)d_out;

  char* p = (char*)d_ws;
  auto alloc = [&](size_t bytes) {
    char* r = p; p += (bytes + 255) & ~(size_t)255; return r;
  };
  u16* wbGates = (u16*)alloc((size_t)4 * DIMN * DIMN * 2);  // f,i,ig,og
  u16* wbWfc  = (u16*)alloc((size_t)FFD * DIMN * 2);
  u16* wbWfa  = (u16*)alloc((size_t)FFD * DIMN * 2);
  u16* wbWfo  = (u16*)alloc((size_t)FFD * DIMN * 2);
  u16* wbWout = (u16*)alloc((size_t)VOCAB * DIMN * 2);
  float* x    = (float*)alloc((size_t)MROWS * DIMN * 4);
  u16* hin    = (u16*)alloc((size_t)MROWS * DIMN * 2);
  float* fbuf = (float*)alloc((size_t)MROWS * DIMN * 4);
  float* vbuf = (float*)alloc((size_t)MROWS * DIMN * 4);
  float* oobuf= (float*)alloc((size_t)MROWS * DIMN * 4);
  u16* ub     = (u16*)alloc((size_t)MROWS * FFD * 2);
  float* pk   = (float*)alloc((size_t)2 * MROWS * DIMN * 4);  // split-K partials
  float* Ac    = (float*)alloc((size_t)2 * NCHUNK * DIMN * 4);
  float* Vc    = (float*)alloc((size_t)2 * NCHUNK * DIMN * 4);
  float* carry = (float*)alloc((size_t)2 * NCHUNK * DIMN * 4);

  u16* wbWf  = wbGates;
  u16* wbWi  = wbGates + (size_t)1 * DIMN * DIMN;
  u16* wbWig = wbGates + (size_t)2 * DIMN * DIMN;
  u16* wbWog = wbGates + (size_t)3 * DIMN * DIMN;

  k_embed<<<dim3(MROWS), dim3(256), 0, stream>>>(tokens, emb, x);

  for (int L = 0; L < D_LAYERS; ++L) {
    k_cvt7<<<dim3(8192), dim3(256), 0, stream>>>(
        Wf, Wi, Wig, Wog, Wfc, Wfa, Wfo,
        wbGates, wbWfc, wbWfa, wbWfo, L);

    k_rms<<<dim3(MROWS), dim3(256), 0, stream>>>(x, n1 + (size_t)L * DIMN, hin);

    // fused gate pairs: y=0 (Wi,Wig)->vbuf ; y=1 (Wf,Wog)->fbuf,oobuf
    gemm_dual<EDG><<<dim3(256, 2), dim3(256), 0, stream>>>(
        hin, wbWi, wbWig, wbWf, wbWog,
        bi_ + (size_t)L * DIMN, big_ + (size_t)L * DIMN,
        bf_ + (size_t)L * DIMN, bog_ + (size_t)L * DIMN,
        vbuf, fbuf, oobuf, nullptr, DIMN, DIMN, 32);

    k_scanA<<<dim3(512), dim3(256), 0, stream>>>(fbuf, vbuf, Ac, Vc);
    k_scanB<<<dim3(8), dim3(256), 0, stream>>>(Ac, Vc, h0 + (size_t)L * DIMN, carry);
    k_scanC<<<dim3(512), dim3(256), 0, stream>>>(fbuf, vbuf, oobuf, carry, x);

    k_rms<<<dim3(MROWS), dim3(256), 0, stream>>>(x, n2 + (size_t)L * DIMN, hin);

    // fused FFN-up: (Wfa,Wfc) -> u = fc * silu(fa)
    gemm_dual<EDF><<<dim3(1024, 1), dim3(256), 0, stream>>>(
        hin, wbWfa, wbWfc, nullptr, nullptr,
        bfa_ + (size_t)L * FFD, bfc_ + (size_t)L * FFD, nullptr, nullptr,
        nullptr, nullptr, nullptr, ub, FFD, DIMN, 32);

    // FFN-down split-K=2 at 128^2 tile (512 blocks), then fused reduce
    gemm_bt<128, EPI_PART><<<dim3(256, 1, 2), dim3(256), 0, stream>>>(
        ub, wbWfo, nullptr, pk, DIMN, FFD / 2, FFD, 32);
    k_red<<<dim3(MROWS), dim3(256), 0, stream>>>(
        (const f32x4*)pk, bfo_ + (size_t)L * DIMN, x);
  }

  k_cvt<<<dim3(16000), dim3(256), 0, stream>>>((const f32x4*)Wout, (u16x8*)wbWout);
  k_rms<<<dim3(MROWS), dim3(256), 0, stream>>>(x, nl_, hin);
  gemm_bt<128, EPI_BIAS_F32><<<dim3(8000), dim3(256), 0, stream>>>(
      hin, wbWout, bout_, out, VOCAB, DIMN, DIMN, 32);
}

// Round 8
// 2088.452 us; speedup vs baseline: 1.0859x; 1.0859x over previous
//
#include <hip/hip_runtime.h>
#include <hip/hip_bf16.h>
#include <cstdint>
#include <cstddef>

typedef unsigned short u16;
typedef __attribute__((ext_vector_type(4))) float f32x4;
typedef __attribute__((ext_vector_type(8))) short bf16x8;
typedef __attribute__((ext_vector_type(8))) unsigned short u16x8;
typedef __attribute__((ext_vector_type(4))) unsigned short u16x4;

#define D_LAYERS 8
#define DIMN 1024
#define FFD 4096
#define VOCAB 32000
#define MROWS 4096   /* B*S */
#define SEQ 2048
#define NCHUNK 64
#define LCHUNK 32

// ---------- helpers ----------
__device__ __forceinline__ u16 f2b(float f) {
  union { float f; unsigned u; } v; v.f = f;
  unsigned r = v.u + 0x7FFFu + ((v.u >> 16) & 1u);
  return (u16)(r >> 16);
}
__device__ __forceinline__ float b2f(u16 h) {
  union { unsigned u; float f; } v; v.u = ((unsigned)h) << 16;
  return v.f;
}
__device__ __forceinline__ float sigm(float x) { return 1.f / (1.f + __expf(-x)); }
__device__ __forceinline__ float ftanh(float x) {
  float e = __expf(2.f * x);          // inf for large x -> 1; 0 for very neg -> -1
  return 1.f - 2.f / (e + 1.f);
}

// async global->LDS, 16B per lane. LDS dest is wave-uniform base + lane*16 (HW).
__device__ __forceinline__ void async16(const void* g, void* l) {
  auto gp = reinterpret_cast<const __attribute__((address_space(1))) char*>(
      reinterpret_cast<uintptr_t>(g));
  auto lp = reinterpret_cast<__attribute__((address_space(3))) char*>(
      reinterpret_cast<uintptr_t>(l));
  __builtin_amdgcn_global_load_lds(gp, lp, 16, 0, 0);
}

__device__ __forceinline__ float blk_sum(float v) {
  __shared__ float sm[4];
  #pragma unroll
  for (int o = 32; o > 0; o >>= 1) v += __shfl_xor(v, o);
  if ((threadIdx.x & 63) == 0) sm[threadIdx.x >> 6] = v;
  __syncthreads();
  float r = sm[0] + sm[1] + sm[2] + sm[3];
  __syncthreads();
  return r;
}

// ---------- small kernels ----------
__global__ __launch_bounds__(256) void k_cvt(const f32x4* __restrict__ in,
                                             u16x8* __restrict__ out) {
  size_t i = (size_t)blockIdx.x * 256 + threadIdx.x;
  f32x4 a = in[i * 2], b = in[i * 2 + 1];
  u16x8 o;
  o[0] = f2b(a[0]); o[1] = f2b(a[1]); o[2] = f2b(a[2]); o[3] = f2b(a[3]);
  o[4] = f2b(b[0]); o[5] = f2b(b[1]); o[6] = f2b(b[2]); o[7] = f2b(b[3]);
  out[i] = o;
}

// converts one layer's 7 weight tensors in one launch (8192 blocks x 2048 elems)
__global__ __launch_bounds__(256) void k_cvt7(
    const float* __restrict__ Wf, const float* __restrict__ Wi,
    const float* __restrict__ Wig, const float* __restrict__ Wog,
    const float* __restrict__ Wfc, const float* __restrict__ Wfa,
    const float* __restrict__ Wfo,
    u16* __restrict__ dGates,   // [4 x 1M] bf16, order f,i,ig,og
    u16* __restrict__ dFc, u16* __restrict__ dFa, u16* __restrict__ dFo,
    int L)
{
  const int b = blockIdx.x;  // 0..8191
  const float* src; u16* dst; size_t off;
  if (b < 2048) {
    const int g = b >> 9, r = b & 511;
    const float* s = (g == 0) ? Wf : (g == 1) ? Wi : (g == 2) ? Wig : Wog;
    src = s + (size_t)L * 1048576;
    dst = dGates + (size_t)g * 1048576;
    off = (size_t)r * 2048;
  } else if (b < 4096) {
    src = Wfc + (size_t)L * 4194304; dst = dFc; off = (size_t)(b - 2048) * 2048;
  } else if (b < 6144) {
    src = Wfa + (size_t)L * 4194304; dst = dFa; off = (size_t)(b - 4096) * 2048;
  } else {
    src = Wfo + (size_t)L * 4194304; dst = dFo; off = (size_t)(b - 6144) * 2048;
  }
  const size_t i = off + (size_t)threadIdx.x * 8;
  f32x4 a = *(const f32x4*)(src + i);
  f32x4 c = *(const f32x4*)(src + i + 4);
  u16x8 o;
  o[0] = f2b(a[0]); o[1] = f2b(a[1]); o[2] = f2b(a[2]); o[3] = f2b(a[3]);
  o[4] = f2b(c[0]); o[5] = f2b(c[1]); o[6] = f2b(c[2]); o[7] = f2b(c[3]);
  *(u16x8*)(dst + i) = o;
}

__global__ __launch_bounds__(256) void k_embed(const int* __restrict__ tok,
                                               const float* __restrict__ emb,
                                               float* __restrict__ x) {
  const int r = blockIdx.x;
  const int tk = tok[r];
  f32x4 v = ((const f32x4*)(emb + (size_t)tk * DIMN))[threadIdx.x];
  float ss = v[0]*v[0] + v[1]*v[1] + v[2]*v[2] + v[3]*v[3];
  float tot = blk_sum(ss);
  float nrm = sqrtf(tot);
  float s = (nrm > 1.f) ? (1.f / (nrm + 1e-7f)) : 1.f;
  f32x4 o = {v[0]*s, v[1]*s, v[2]*s, v[3]*s};
  ((f32x4*)(x + (size_t)r * DIMN))[threadIdx.x] = o;
}

__global__ __launch_bounds__(256) void k_rms(const float* __restrict__ x,
                                             const float* __restrict__ wgt,
                                             u16* __restrict__ out) {
  const int r = blockIdx.x;
  f32x4 v = ((const f32x4*)(x + (size_t)r * DIMN))[threadIdx.x];
  float ss = v[0]*v[0] + v[1]*v[1] + v[2]*v[2] + v[3]*v[3];
  float tot = blk_sum(ss);
  float sc = rsqrtf(tot * (1.f / DIMN) + 1e-6f);
  f32x4 w = ((const f32x4*)wgt)[threadIdx.x];
  u16x4 o;
  o[0] = f2b(v[0] * sc * w[0]);
  o[1] = f2b(v[1] * sc * w[1]);
  o[2] = f2b(v[2] * sc * w[2]);
  o[3] = f2b(v[3] * sc * w[3]);
  ((u16x4*)(out + (size_t)r * DIMN))[threadIdx.x] = o;
}

// scan phase A: per-chunk aggregates (A = prod f, V = chunk-local scan end)
__global__ __launch_bounds__(256) void k_scanA(const float* __restrict__ f,
                                               const float* __restrict__ v,
                                               float* __restrict__ Ac,
                                               float* __restrict__ Vc) {
  const int bx = blockIdx.x;              // b*256 + c*4 + dg
  const int dg = bx & 3, c = (bx >> 2) & 63, b = bx >> 8;
  const int d = dg * 256 + threadIdx.x;
  const size_t base = ((size_t)(b * SEQ + c * LCHUNK)) * DIMN + d;
  float a = 1.f, h = 0.f;
  #pragma unroll 4
  for (int t = 0; t < LCHUNK; ++t) {
    size_t ix = base + (size_t)t * DIMN;
    float fv = f[ix];
    h = fv * h + v[ix];
    a *= fv;
  }
  const size_t ci = ((size_t)(b * NCHUNK + c)) * DIMN + d;
  Ac[ci] = a; Vc[ci] = h;
}

// scan phase B: exclusive scan over chunks, init = h0
__global__ __launch_bounds__(256) void k_scanB(const float* __restrict__ Ac,
                                               const float* __restrict__ Vc,
                                               const float* __restrict__ h0,
                                               float* __restrict__ carry) {
  const int idx = blockIdx.x * 256 + threadIdx.x;  // 0..2047
  const int b = idx >> 10, d = idx & 1023;
  float h = h0[d];
  for (int c = 0; c < NCHUNK; ++c) {
    size_t ci = ((size_t)(b * NCHUNK + c)) * DIMN + d;
    carry[ci] = h;
    h = Ac[ci] * h + Vc[ci];
  }
}

// scan phase C: recompute with carry-in, y = tanh(h)*o, x += y
__global__ __launch_bounds__(256) void k_scanC(const float* __restrict__ f,
                                               const float* __restrict__ v,
                                               const float* __restrict__ oo,
                                               const float* __restrict__ carry,
                                               float* __restrict__ x) {
  const int bx = blockIdx.x;
  const int dg = bx & 3, c = (bx >> 2) & 63, b = bx >> 8;
  const int d = dg * 256 + threadIdx.x;
  const size_t base = ((size_t)(b * SEQ + c * LCHUNK)) * DIMN + d;
  float h = carry[((size_t)(b * NCHUNK + c)) * DIMN + d];
  for (int t = 0; t < LCHUNK; ++t) {
    size_t ix = base + (size_t)t * DIMN;
    float fv = f[ix];
    h = fv * h + v[ix];
    x[ix] += ftanh(h) * oo[ix];
  }
}

// split-K reduce: x += p0 + p1 + bias
__global__ __launch_bounds__(256) void k_red(const f32x4* __restrict__ pp,
                                             const float* __restrict__ bias,
                                             float* __restrict__ x) {
  const size_t i = (size_t)blockIdx.x * 256 + threadIdx.x;   // f32x4 index
  const int n4 = (int)(i & 255);                             // DIMN/4 = 256
  f32x4 a = pp[i];
  f32x4 b = pp[i + (size_t)MROWS * DIMN / 4];
  f32x4 bs = ((const f32x4*)bias)[n4];
  f32x4 xv = ((const f32x4*)x)[i];
  f32x4 o = {xv[0] + a[0] + b[0] + bs[0], xv[1] + a[1] + b[1] + bs[1],
             xv[2] + a[2] + b[2] + bs[2], xv[3] + a[3] + b[3] + bs[3]};
  ((f32x4*)x)[i] = o;
}

// ---------- 128-tile GEMM (m97 structure; 2D grid x=m-fastest) ----------
// x=m-fastest gives each XCD a FIXED m-slice of A pinned in its L2 while B
// panels stream through L3 (round-7 lesson: n-chunked swizzle thrashes A).
constexpr int EPI_BIAS_F32 = 4, EPI_PART = 5;

template<int BN_T, int EPI>
__global__ __launch_bounds__(256, 2)
void gemm_bt(const u16* __restrict__ A,
             const u16* __restrict__ B0,
             const float* __restrict__ bias0,
             float* __restrict__ oF0,
             int N, int K, int LD)
{
  constexpr int MF = (BN_T == 128) ? 4 : 2;
  constexpr int WAVES_N = (BN_T == 128) ? 2 : 1;
  constexpr int ISS_B = BN_T / 32;
  __shared__ __align__(16) u16 As[128 * 64];
  __shared__ __align__(16) u16 Bs[BN_T * 64];
  const int tid = threadIdx.x;
  const int w = tid >> 6, lane = tid & 63;
  const int wm = w / WAVES_N, wn = w % WAVES_N;
  const int m0 = blockIdx.x * 128;
  const int n0 = blockIdx.y * BN_T;

  const u16* Aw = A;
  const u16* Bw = B0;
  float* oF = oF0;
  if constexpr (EPI == EPI_PART) {
    const int koff = blockIdx.z * K;       // split-K column offset
    Aw += koff; Bw += koff;
    oF += (size_t)blockIdx.z * MROWS * DIMN;
  }

  const f32x4 zero = {0.f, 0.f, 0.f, 0.f};
  f32x4 acc[MF][4];
  #pragma unroll
  for (int mf = 0; mf < MF; ++mf)
    #pragma unroll
    for (int nf = 0; nf < 4; ++nf) acc[mf][nf] = zero;

  for (int kt = 0; kt < K; kt += 64) {
    #pragma unroll
    for (int i = 0; i < 4; ++i) {
      int p = i * 4096 + w * 1024 + lane * 16;
      int r = p >> 7;
      int cs = (p & 127) ^ ((r & 7) << 4);
      async16(Aw + ((size_t)(m0 + r) * LD + kt) + (cs >> 1),
              (char*)As + i * 4096 + w * 1024);
    }
    #pragma unroll
    for (int i = 0; i < ISS_B; ++i) {
      int p = i * 4096 + w * 1024 + lane * 16;
      int r = p >> 7;
      int cs = (p & 127) ^ ((r & 7) << 4);
      async16(Bw + ((size_t)(n0 + r) * LD + kt) + (cs >> 1),
              (char*)Bs + i * 4096 + w * 1024);
    }
    __syncthreads();
    #pragma unroll
    for (int ks = 0; ks < 2; ++ks) {
      bf16x8 av[MF], bv[4];
      const int cbase = ks * 64 + ((lane >> 4) << 4);
      #pragma unroll
      for (int mf = 0; mf < MF; ++mf) {
        int r = wm * (MF * 16) + mf * 16 + (lane & 15);
        av[mf] = *(const bf16x8*)((const char*)As + r * 128 + (cbase ^ ((r & 7) << 4)));
      }
      #pragma unroll
      for (int nf = 0; nf < 4; ++nf) {
        int r = wn * 64 + nf * 16 + (lane & 15);
        bv[nf] = *(const bf16x8*)((const char*)Bs + r * 128 + (cbase ^ ((r & 7) << 4)));
      }
      #pragma unroll
      for (int mf = 0; mf < MF; ++mf)
        #pragma unroll
        for (int nf = 0; nf < 4; ++nf)
          acc[mf][nf] = __builtin_amdgcn_mfma_f32_16x16x32_bf16(
              av[mf], bv[nf], acc[mf][nf], 0, 0, 0);
    }
    __syncthreads();
  }

  #pragma unroll
  for (int nf = 0; nf < 4; ++nf) {
    const int n = n0 + wn * 64 + nf * 16 + (lane & 15);
    const float bb = (EPI == EPI_PART) ? 0.f : bias0[n];
    #pragma unroll
    for (int mf = 0; mf < MF; ++mf) {
      #pragma unroll
      for (int j = 0; j < 4; ++j) {
        const int m = m0 + wm * (MF * 16) + mf * 16 + ((lane >> 4) << 2) + j;
        const size_t idx = (size_t)m * N + n;
        oF[idx] = acc[mf][nf][j] + bb;
      }
    }
  }
}

// ---------- dual-B 128-tile GEMM: two GEMMs sharing the A-tile ----------
//   EDG (gates, z-routed): z=0: (Wi,Wig) -> v = tanh(va)*sig(vb)
//                          z=1: (Wf,Wog) -> f = sig(va), o = sig(vb)
//   EDF (ffn-up): (Wfa,Wfc) -> u = vb * silu(va)  [bf16]
constexpr int EDG = 0, EDF = 1;

template<int EPI>
__global__ __launch_bounds__(256, 2)
void gemm_dual(const u16* __restrict__ A,
               const u16* __restrict__ Ba0, const u16* __restrict__ Bb0,
               const u16* __restrict__ Ba1, const u16* __restrict__ Bb1,
               const float* __restrict__ ba0, const float* __restrict__ bb0,
               const float* __restrict__ ba1, const float* __restrict__ bb1,
               float* __restrict__ oV,          // z=0 product (gates)
               float* __restrict__ oFa, float* __restrict__ oFb, // z=1 pair
               u16* __restrict__ oU,            // ffn-up bf16
               int N, int K)
{
  __shared__ __align__(16) u16 As[128 * 64];
  __shared__ __align__(16) u16 Bsa[128 * 64];
  __shared__ __align__(16) u16 Bsb[128 * 64];
  const int tid = threadIdx.x;
  const int w = tid >> 6, lane = tid & 63;
  const int wm = w >> 1, wn = w & 1;
  const int m0 = blockIdx.x * 128;
  const int n0 = blockIdx.y * 128;
  const int z = blockIdx.z;

  const u16* Ba = (EPI == EDG && z) ? Ba1 : Ba0;
  const u16* Bb = (EPI == EDG && z) ? Bb1 : Bb0;
  const float* ba = (EPI == EDG && z) ? ba1 : ba0;
  const float* bb = (EPI == EDG && z) ? bb1 : bb0;

  const f32x4 zero = {0.f, 0.f, 0.f, 0.f};
  f32x4 accA[4][4], accB[4][4];
  #pragma unroll
  for (int mf = 0; mf < 4; ++mf)
    #pragma unroll
    for (int nf = 0; nf < 4; ++nf) { accA[mf][nf] = zero; accB[mf][nf] = zero; }

  for (int kt = 0; kt < K; kt += 64) {
    #pragma unroll
    for (int i = 0; i < 4; ++i) {
      const int p = i * 4096 + w * 1024 + lane * 16;
      const int r = p >> 7;
      const int cs = (p & 127) ^ ((r & 7) << 4);
      async16(A  + ((size_t)(m0 + r) * K + kt) + (cs >> 1),
              (char*)As + i * 4096 + w * 1024);
      async16(Ba + ((size_t)(n0 + r) * K + kt) + (cs >> 1),
              (char*)Bsa + i * 4096 + w * 1024);
      async16(Bb + ((size_t)(n0 + r) * K + kt) + (cs >> 1),
              (char*)Bsb + i * 4096 + w * 1024);
    }
    __syncthreads();
    #pragma unroll
    for (int ks = 0; ks < 2; ++ks) {
      bf16x8 av[4], bva[4], bvb[4];
      const int cbase = ks * 64 + ((lane >> 4) << 4);
      #pragma unroll
      for (int mf = 0; mf < 4; ++mf) {
        const int r = wm * 64 + mf * 16 + (lane & 15);
        av[mf] = *(const bf16x8*)((const char*)As + r * 128 + (cbase ^ ((r & 7) << 4)));
      }
      #pragma unroll
      for (int nf = 0; nf < 4; ++nf) {
        const int r = wn * 64 + nf * 16 + (lane & 15);
        const int off = r * 128 + (cbase ^ ((r & 7) << 4));
        bva[nf] = *(const bf16x8*)((const char*)Bsa + off);
        bvb[nf] = *(const bf16x8*)((const char*)Bsb + off);
      }
      #pragma unroll
      for (int mf = 0; mf < 4; ++mf)
        #pragma unroll
        for (int nf = 0; nf < 4; ++nf) {
          accA[mf][nf] = __builtin_amdgcn_mfma_f32_16x16x32_bf16(
              av[mf], bva[nf], accA[mf][nf], 0, 0, 0);
          accB[mf][nf] = __builtin_amdgcn_mfma_f32_16x16x32_bf16(
              av[mf], bvb[nf], accB[mf][nf], 0, 0, 0);
        }
    }
    __syncthreads();
  }

  #pragma unroll
  for (int nf = 0; nf < 4; ++nf) {
    const int n = n0 + wn * 64 + nf * 16 + (lane & 15);
    const float bba = ba[n], bbb = bb[n];
    #pragma unroll
    for (int mf = 0; mf < 4; ++mf) {
      #pragma unroll
      for (int j = 0; j < 4; ++j) {
        const int m = m0 + wm * 64 + mf * 16 + ((lane >> 4) << 2) + j;
        const size_t idx = (size_t)m * N + n;
        const float va = accA[mf][nf][j] + bba;
        const float vb = accB[mf][nf][j] + bbb;
        if constexpr (EPI == EDG) {
          if (z == 0) {
            oV[idx] = ftanh(va) * sigm(vb);
          } else {
            oFa[idx] = sigm(va);
            oFb[idx] = sigm(vb);
          }
        } else {
          oU[idx] = f2b(vb * va * sigm(va));
        }
      }
    }
  }
}

// ---------- launcher ----------
extern "C" void kernel_launch(void* const* d_in, const int* in_sizes, int n_in,
                              void* d_out, int out_size, void* d_ws, size_t ws_size,
                              hipStream_t stream) {
  (void)in_sizes; (void)n_in; (void)out_size; (void)ws_size;
  const int*   tokens = (const int*)d_in[0];
  const float* emb  = (const float*)d_in[1];
  const float* h0   = (const float*)d_in[2];
  const float* Wf   = (const float*)d_in[3];
  const float* bf_  = (const float*)d_in[4];
  const float* Wi   = (const float*)d_in[5];
  const float* bi_  = (const float*)d_in[6];
  const float* Wig  = (const float*)d_in[7];
  const float* big_ = (const float*)d_in[8];
  const float* Wog  = (const float*)d_in[9];
  const float* bog_ = (const float*)d_in[10];
  const float* n1   = (const float*)d_in[11];
  const float* n2   = (const float*)d_in[12];
  const float* Wfc  = (const float*)d_in[13];
  const float* bfc_ = (const float*)d_in[14];
  const float* Wfa  = (const float*)d_in[15];
  const float* bfa_ = (const float*)d_in[16];
  const float* Wfo  = (const float*)d_in[17];
  const float* bfo_ = (const float*)d_in[18];
  const float* nl_  = (const float*)d_in[19];
  const float* Wout = (const float*)d_in[20];
  const float* bout_= (const float*)d_in[21];
  float* out = (float*)d_out;

  char* p = (char*)d_ws;
  auto alloc = [&](size_t bytes) {
    char* r = p; p += (bytes + 255) & ~(size_t)255; return r;
  };
  u16* wbGates = (u16*)alloc((size_t)4 * DIMN * DIMN * 2);  // f,i,ig,og
  u16* wbWfc  = (u16*)alloc((size_t)FFD * DIMN * 2);
  u16* wbWfa  = (u16*)alloc((size_t)FFD * DIMN * 2);
  u16* wbWfo  = (u16*)alloc((size_t)FFD * DIMN * 2);
  u16* wbWout = (u16*)alloc((size_t)VOCAB * DIMN * 2);
  float* x    = (float*)alloc((size_t)MROWS * DIMN * 4);
  u16* hin    = (u16*)alloc((size_t)MROWS * DIMN * 2);
  float* fbuf = (float*)alloc((size_t)MROWS * DIMN * 4);
  float* vbuf = (float*)alloc((size_t)MROWS * DIMN * 4);
  float* oobuf= (float*)alloc((size_t)MROWS * DIMN * 4);
  u16* ub     = (u16*)alloc((size_t)MROWS * FFD * 2);
  float* pk   = (float*)alloc((size_t)2 * MROWS * DIMN * 4);  // split-K partials
  float* Ac    = (float*)alloc((size_t)2 * NCHUNK * DIMN * 4);
  float* Vc    = (float*)alloc((size_t)2 * NCHUNK * DIMN * 4);
  float* carry = (float*)alloc((size_t)2 * NCHUNK * DIMN * 4);

  u16* wbWf  = wbGates;
  u16* wbWi  = wbGates + (size_t)1 * DIMN * DIMN;
  u16* wbWig = wbGates + (size_t)2 * DIMN * DIMN;
  u16* wbWog = wbGates + (size_t)3 * DIMN * DIMN;

  k_embed<<<dim3(MROWS), dim3(256), 0, stream>>>(tokens, emb, x);

  for (int L = 0; L < D_LAYERS; ++L) {
    k_cvt7<<<dim3(8192), dim3(256), 0, stream>>>(
        Wf, Wi, Wig, Wog, Wfc, Wfa, Wfo,
        wbGates, wbWfc, wbWfa, wbWfo, L);

    k_rms<<<dim3(MROWS), dim3(256), 0, stream>>>(x, n1 + (size_t)L * DIMN, hin);

    // fused gate pairs: z=0 (Wi,Wig)->vbuf ; z=1 (Wf,Wog)->fbuf,oobuf
    gemm_dual<EDG><<<dim3(32, 8, 2), dim3(256), 0, stream>>>(
        hin, wbWi, wbWig, wbWf, wbWog,
        bi_ + (size_t)L * DIMN, big_ + (size_t)L * DIMN,
        bf_ + (size_t)L * DIMN, bog_ + (size_t)L * DIMN,
        vbuf, fbuf, oobuf, nullptr, DIMN, DIMN);

    k_scanA<<<dim3(512), dim3(256), 0, stream>>>(fbuf, vbuf, Ac, Vc);
    k_scanB<<<dim3(8), dim3(256), 0, stream>>>(Ac, Vc, h0 + (size_t)L * DIMN, carry);
    k_scanC<<<dim3(512), dim3(256), 0, stream>>>(fbuf, vbuf, oobuf, carry, x);

    k_rms<<<dim3(MROWS), dim3(256), 0, stream>>>(x, n2 + (size_t)L * DIMN, hin);

    // fused FFN-up: (Wfa,Wfc) -> u = fc * silu(fa)
    gemm_dual<EDF><<<dim3(32, 32, 1), dim3(256), 0, stream>>>(
        hin, wbWfa, wbWfc, nullptr, nullptr,
        bfa_ + (size_t)L * FFD, bfc_ + (size_t)L * FFD, nullptr, nullptr,
        nullptr, nullptr, nullptr, ub, FFD, DIMN);

    // FFN-down split-K=2 at 128^2 tile (2D grid, z=K-part), then fused reduce
    gemm_bt<128, EPI_PART><<<dim3(32, 8, 2), dim3(256), 0, stream>>>(
        ub, wbWfo, nullptr, pk, DIMN, FFD / 2, FFD);
    k_red<<<dim3(MROWS), dim3(256), 0, stream>>>(
        (const f32x4*)pk, bfo_ + (size_t)L * DIMN, x);
  }

  k_cvt<<<dim3(16000), dim3(256), 0, stream>>>((const f32x4*)Wout, (u16x8*)wbWout);
  k_rms<<<dim3(MROWS), dim3(256), 0, stream>>>(x, nl_, hin);
  gemm_bt<128, EPI_BIAS_F32><<<dim3(32, 250), dim3(256), 0, stream>>>(
      hin, wbWout, bout_, out, VOCAB, DIMN, DIMN);
}